// Round 2
// 320.064 us; speedup vs baseline: 1.0202x; 1.0202x over previous
//
// Round 8 (resubmit — R1 bench failed on GPU acquisition, no data):
// transposed trace layout — swap MFMA operands (mfma(W, X)) so the
// C-layout puts batch-row in l15 and feature cols in regs. Row reductions
// become in-thread sums + 2 shfl_xor + 1 atomic (was 4x red16 DPP chains +
// serialized atomic loops); LDS staging is packed ds_write_b64 with a
// slot-XOR swizzle (verified 4-phase writes / 8-phase reads, conflict-free);
// gv/vv broadcast is one b64 read; global loads vectorized to float4.
// Weight-frag addressing identical to round 7 (A-frag == old B-frag pattern),
// so prep/GEMMs unchanged. memset folded into prep_all. 4 dispatches.

#include <hip/hip_runtime.h>
#include <math.h>

typedef short bf8 __attribute__((ext_vector_type(8)));   // 8 bf16 = 4 VGPR
typedef short s4v __attribute__((ext_vector_type(4)));   // 4 bf16 = 8 B
typedef float f32x4 __attribute__((ext_vector_type(4))); // MFMA acc

namespace {

constexpr float H_STEP = 1.0f / 15.0f;

__device__ inline short f2bf(float f) {  // RNE f32 -> bf16
  unsigned u = __float_as_uint(f);
  u += 0x7fffu + ((u >> 16) & 1u);
  return (short)(u >> 16);
}

__device__ inline float fast_tanh(float x) {
  const float ax = fabsf(x);
  const float e = __expf(-2.0f * ax);
  const float t = (1.0f - e) * __builtin_amdgcn_rcpf(1.0f + e);
  return copysignf(t, x);
}

// 1 - tanh(x)^2 = 4 e / (1+e)^2, e = exp(-2|x|)
__device__ inline float sech2(float x) {
  const float e = __expf(-2.0f * fabsf(x));
  const float r = __builtin_amdgcn_rcpf(1.0f + e);
  return 4.0f * e * r * r;
}

// sum over each 16-lane group via DPP row_ror 1/2/4/8 (final output reduce)
template <int CTRL>
__device__ inline float dppadd(float v) {
  return v + __int_as_float(__builtin_amdgcn_update_dpp(
                 0, __float_as_int(v), CTRL, 0xF, 0xF, true));
}
__device__ inline float red16(float v) {
  v = dppadd<0x121>(v);
  v = dppadd<0x122>(v);
  v = dppadd<0x124>(v);
  v = dppadd<0x128>(v);
  return v;
}

// async global->LDS, 16B per lane. LDS dest = wave-uniform base + lane*16.
__device__ inline void async16(const void* g, void* l) {
  __builtin_amdgcn_global_load_lds((__attribute__((address_space(1))) void*)g,
                                   (__attribute__((address_space(3))) void*)l,
                                   16, 0, 0);
}

// pack 4 f32 -> 4 bf16, single ds_write_b64 at byte offset
__device__ inline void stpk4(short* base, int byteoff, float a, float b,
                             float c, float d) {
  s4v s;
  s[0] = f2bf(a);
  s[1] = f2bf(b);
  s[2] = f2bf(c);
  s[3] = f2bf(d);
  *(s4v*)((char*)base + byteoff) = s;
}

// ---------------- one-shot prep: inputs + all weight converts ----------------
// blocks [0,2048): x_start/x_end -> XSb [8192][2048] bf16 (grid-stride x8)
// [2048,4096): W1^T  [4096,4352): W2^T  [4352,4416): Ww1^T
// [4416,4480): Ww2^T [4480,4544): Wp1^T [4544,4608): wp2-scaled Wp1 copy
__global__ __launch_bounds__(256) void prep_all(
    const float* __restrict__ xs, const float* __restrict__ xe,
    const float* __restrict__ W1, const float* __restrict__ W2,
    const float* __restrict__ Ww1, const float* __restrict__ Ww2,
    const float* __restrict__ Wp1, const float* __restrict__ wp2,
    short* __restrict__ XSb, short* __restrict__ W1T, short* __restrict__ W2T,
    short* __restrict__ Ww1T, short* __restrict__ Ww2T,
    short* __restrict__ WpT, short* __restrict__ Wp1s,
    float* __restrict__ outz) {
  __shared__ float tile[32][33];
  const int id = blockIdx.x;
  if (id < 2048) {
    if (id == 0 && threadIdx.x == 0) *outz = 0.0f;  // folded memset
    const long n = (long)8192 * 2048, half = n >> 1;
    long i = ((long)id * 256 + threadIdx.x) * 4;
    const long stride = (long)2048 * 1024;
    for (; i < n; i += stride) {
      const float* s = (i < half) ? (xs + i) : (xe + (i - half));
      const float4 f = *(const float4*)s;
      ushort4 o;
      o.x = (unsigned short)f2bf(f.x);
      o.y = (unsigned short)f2bf(f.y);
      o.z = (unsigned short)f2bf(f.z);
      o.w = (unsigned short)f2bf(f.w);
      *(ushort4*)(XSb + i) = o;
    }
    return;
  }
  const int tr = threadIdx.x >> 5, tc = threadIdx.x & 31;
  const float* src;
  short* dst;
  int K, N, kt, nt;
  if (id < 4096) {
    src = W1; dst = W1T; K = 2048; N = 1024; kt = (id - 2048) >> 5; nt = (id - 2048) & 31;
  } else if (id < 4352) {
    src = W2; dst = W2T; K = 1024; N = 256; kt = (id - 4096) >> 3; nt = (id - 4096) & 7;
  } else if (id < 4416) {
    src = Ww1; dst = Ww1T; K = 256; N = 256; kt = (id - 4352) >> 3; nt = (id - 4352) & 7;
  } else if (id < 4480) {
    src = Ww2; dst = Ww2T; K = 256; N = 256; kt = (id - 4416) >> 3; nt = (id - 4416) & 7;
  } else if (id < 4544) {
    src = Wp1; dst = WpT; K = 256; N = 256; kt = (id - 4480) >> 3; nt = (id - 4480) & 7;
  } else {  // wp2-scaled row-major copy
    const int lid = id - 4544;
    const int k0 = (lid >> 3) * 32, n0 = (lid & 7) * 32;
#pragma unroll
    for (int i = 0; i < 32; i += 8) {
      const size_t o = (size_t)(k0 + tr + i) * 256 + n0 + tc;
      Wp1s[o] = f2bf(Wp1[o] * wp2[n0 + tc]);
    }
    return;
  }
  const int k0 = kt * 32, n0 = nt * 32;
#pragma unroll
  for (int i = 0; i < 32; i += 8)
    tile[tr + i][tc] = src[(size_t)(k0 + tr + i) * N + n0 + tc];
  __syncthreads();
#pragma unroll
  for (int i = 0; i < 32; i += 8)
    dst[(size_t)(n0 + tr + i) * K + k0 + tc] = f2bf(tile[tc][tr + i]);
}

// ---------------- bf16 TN GEMMs, global_load_lds staging ----------------

// 128x128 tile, BK=64, tanh->bf16 epilogue (encoder L1)
__global__ __launch_bounds__(256) void gemm128_tanh(
    const short* __restrict__ A, const short* __restrict__ Bt,
    const float* __restrict__ bias, short* __restrict__ Cb, int M, int N,
    int K) {
  __shared__ __align__(16) short As[2 * 128 * 32];
  __shared__ __align__(16) short Bs[2 * 128 * 32];
  const int tid = threadIdx.x;
  const int w = tid >> 6, lane = tid & 63, q = lane >> 4, l15 = lane & 15;
  const int wm = (w >> 1) * 64, wn = (w & 1) * 64;
  const int m0 = blockIdx.y * 128, n0 = blockIdx.x * 128;
  const f32x4 fzero = {0.0f, 0.0f, 0.0f, 0.0f};
  f32x4 acc[4][4];
#pragma unroll
  for (int mt = 0; mt < 4; ++mt)
#pragma unroll
    for (int nt = 0; nt < 4; ++nt) acc[mt][nt] = fzero;

  for (int k0 = 0; k0 < K; k0 += 64) {
#pragma unroll
    for (int kcb = 0; kcb < 2; ++kcb)
#pragma unroll
      for (int j = 0; j < 2; ++j) {
        const int c = w * 128 + j * 64 + lane;
        async16(A + (size_t)(m0 + (c >> 2)) * K + k0 + kcb * 32 + (c & 3) * 8,
                &As[kcb * 4096 + (w * 128 + j * 64) * 8]);
        async16(Bt + (size_t)(n0 + (c >> 2)) * K + k0 + kcb * 32 + (c & 3) * 8,
                &Bs[kcb * 4096 + (w * 128 + j * 64) * 8]);
      }
    __syncthreads();
#pragma unroll
    for (int kcb = 0; kcb < 2; ++kcb) {
      bf8 af[4], bfr[4];
#pragma unroll
      for (int mt = 0; mt < 4; ++mt)
        af[mt] =
            *(const bf8*)&As[kcb * 4096 + (wm + mt * 16 + l15) * 32 + q * 8];
#pragma unroll
      for (int nt = 0; nt < 4; ++nt)
        bfr[nt] =
            *(const bf8*)&Bs[kcb * 4096 + (wn + nt * 16 + l15) * 32 + q * 8];
#pragma unroll
      for (int mt = 0; mt < 4; ++mt)
#pragma unroll
        for (int nt = 0; nt < 4; ++nt)
          acc[mt][nt] = __builtin_amdgcn_mfma_f32_16x16x32_bf16(
              af[mt], bfr[nt], acc[mt][nt], 0, 0, 0);
    }
    __syncthreads();
  }
#pragma unroll
  for (int mt = 0; mt < 4; ++mt)
#pragma unroll
    for (int nt = 0; nt < 4; ++nt) {
      const int col = n0 + wn + nt * 16 + l15;
      const float bcol = bias[col];
#pragma unroll
      for (int rg = 0; rg < 4; ++rg) {
        const int row = m0 + wm + mt * 16 + q * 4 + rg;
        Cb[(size_t)row * N + col] = f2bf(fast_tanh(acc[mt][nt][rg] + bcol));
      }
    }
}

// 64x64 tile, BK=64; rows<4096 -> z_s, rows>=4096 -> z_e (both f32)
__global__ __launch_bounds__(256) void gemm64_enc2(
    const short* __restrict__ A, const short* __restrict__ Bt,
    const float* __restrict__ bias, float* __restrict__ Zs,
    float* __restrict__ Ze, int M, int N, int K) {
  __shared__ __align__(16) short As[2 * 64 * 32];
  __shared__ __align__(16) short Bs[2 * 64 * 32];
  const int tid = threadIdx.x;
  const int w = tid >> 6, lane = tid & 63, q = lane >> 4, l15 = lane & 15;
  const int wm = (w >> 1) * 32, wn = (w & 1) * 32;
  const int m0 = blockIdx.y * 64, n0 = blockIdx.x * 64;
  const f32x4 fzero = {0.0f, 0.0f, 0.0f, 0.0f};
  f32x4 acc[2][2];
#pragma unroll
  for (int mt = 0; mt < 2; ++mt)
#pragma unroll
    for (int nt = 0; nt < 2; ++nt) acc[mt][nt] = fzero;

  for (int k0 = 0; k0 < K; k0 += 64) {
    const int c = w * 64 + lane;
#pragma unroll
    for (int kcb = 0; kcb < 2; ++kcb) {
      async16(A + (size_t)(m0 + (c >> 2)) * K + k0 + kcb * 32 + (c & 3) * 8,
              &As[kcb * 2048 + (w * 64) * 8]);
      async16(Bt + (size_t)(n0 + (c >> 2)) * K + k0 + kcb * 32 + (c & 3) * 8,
              &Bs[kcb * 2048 + (w * 64) * 8]);
    }
    __syncthreads();
#pragma unroll
    for (int kcb = 0; kcb < 2; ++kcb) {
      bf8 af[2], bfr[2];
#pragma unroll
      for (int mt = 0; mt < 2; ++mt)
        af[mt] =
            *(const bf8*)&As[kcb * 2048 + (wm + mt * 16 + l15) * 32 + q * 8];
#pragma unroll
      for (int nt = 0; nt < 2; ++nt)
        bfr[nt] =
            *(const bf8*)&Bs[kcb * 2048 + (wn + nt * 16 + l15) * 32 + q * 8];
#pragma unroll
      for (int mt = 0; mt < 2; ++mt)
#pragma unroll
        for (int nt = 0; nt < 2; ++nt)
          acc[mt][nt] = __builtin_amdgcn_mfma_f32_16x16x32_bf16(
              af[mt], bfr[nt], acc[mt][nt], 0, 0, 0);
    }
    __syncthreads();
  }
#pragma unroll
  for (int mt = 0; mt < 2; ++mt)
#pragma unroll
    for (int nt = 0; nt < 2; ++nt) {
      const int col = n0 + wn + nt * 16 + l15;
      const float bcol = bias[col];
#pragma unroll
      for (int rg = 0; rg < 4; ++rg) {
        const int row = m0 + wm + mt * 16 + q * 4 + rg;
        const float val = acc[mt][nt][rg] + bcol;
        if (row < 4096)
          Zs[(size_t)row * N + col] = val;
        else
          Ze[(size_t)(row - 4096) * N + col] = val;
      }
    }
}

// ---------------- fused wind + fallback + trace (transposed layout) ----------
// 256 blocks x 512 threads. MFMA operands swapped: D = W_frag * X_frag, so
// C-layout gives row r = l15, cols c = w*32 + t*16 + q*4 + rg. Per-row
// reductions: in-thread 8-term sum + shfl_xor(16,32) + 1 LDS atomic (q==0).
// LDS tiles [16 rows][256 bf16 cols], 16B-slot XOR swizzle
// slot' = slot ^ (((r&7)<<2)^(r&3)): b64 writes 4-phase, b128 reads 8-phase.

__global__ __launch_bounds__(512, 2) void trace_fused(
    const float* __restrict__ Xg, const float* __restrict__ ZEg,
    const float* __restrict__ NZg, const short* __restrict__ WT,
    const short* __restrict__ Wp1s, const short* __restrict__ Ww1T,
    const short* __restrict__ Ww2T, const float* __restrict__ bw1,
    const float* __restrict__ bw2, const float* __restrict__ bp1,
    float* __restrict__ out) {
  constexpr float hs = H_STEP;
  __shared__ __align__(16) short XsL[4096];
  __shared__ __align__(16) short UL[4096];
  __shared__ __align__(16) float gvv[2][16][2];  // [parity][row][gv, vv]
  __shared__ __align__(16) float db[2][16];
  const int tid = threadIdx.x;
  const int w = tid >> 6, lane = tid & 63, q = lane >> 4, l15 = lane & 15;
  const int r0 = blockIdx.x * 16;
  const int col0 = w * 32 + q * 4;   // feature-col base (t adds 16, rg adds)
  const int wrow = w * 32 + l15;     // weight-frag row base (t adds 16)

  if (tid < 16) {
    *(float2*)gvv[0][tid] = make_float2(0.f, 0.f);
    *(float2*)gvv[1][tid] = make_float2(0.f, 0.f);
    db[0][tid] = 0.f;
    db[1][tid] = 0.f;
  }

  // LDS addresses (bytes). Shared by XsL and UL (same geometry).
  const int smask = ((l15 & 7) << 2) ^ (l15 & 3);
  int wadrT[2], radrT[8];
#pragma unroll
  for (int t = 0; t < 2; ++t) {
    const int slot = w * 4 + t * 2 + (q >> 1);
    wadrT[t] = (l15 * 32 + (slot ^ smask)) * 16 + (q & 1) * 8;
  }
#pragma unroll
  for (int ks = 0; ks < 8; ++ks)
    radrT[ks] = (l15 * 32 + ((ks * 4 + q) ^ smask)) * 16;

  float x[2][4], ze[2][4], nz[2][4];
#pragma unroll
  for (int t = 0; t < 2; ++t) {
    const size_t off = (size_t)(r0 + l15) * 256 + col0 + t * 16;
    const float4 xa = *(const float4*)(Xg + off);
    const float4 za = *(const float4*)(ZEg + off);
    const float4 na = *(const float4*)(NZg + off);
    x[t][0] = xa.x; x[t][1] = xa.y; x[t][2] = xa.z; x[t][3] = xa.w;
    ze[t][0] = za.x; ze[t][1] = za.y; ze[t][2] = za.z; ze[t][3] = za.w;
    nz[t][0] = na.x; nz[t][1] = na.y; nz[t][2] = na.z; nz[t][3] = na.w;
  }
  float bp1c[2][4];
#pragma unroll
  for (int t = 0; t < 2; ++t) {
    const float4 pa = *(const float4*)(bp1 + col0 + t * 16);
    bp1c[t][0] = pa.x; bp1c[t][1] = pa.y; bp1c[t][2] = pa.z; bp1c[t][3] = pa.w;
  }
  const f32x4 fzero = {0.0f, 0.0f, 0.0f, 0.0f};

  // ---- wind MLP + degenerate-wind fallback ----
  float v[2][4];
  {
    bf8 Wf1[2][8], Wf2[2][8];
#pragma unroll
    for (int t = 0; t < 2; ++t)
#pragma unroll
      for (int ks = 0; ks < 8; ++ks) {
        Wf1[t][ks] =
            *(const bf8*)(Ww1T + (size_t)(wrow + t * 16) * 256 + ks * 32 + q * 8);
        Wf2[t][ks] =
            *(const bf8*)(Ww2T + (size_t)(wrow + t * 16) * 256 + ks * 32 + q * 8);
      }
    float bw1c[2][4], bw2c[2][4];
#pragma unroll
    for (int t = 0; t < 2; ++t) {
      const float4 a1 = *(const float4*)(bw1 + col0 + t * 16);
      const float4 a2 = *(const float4*)(bw2 + col0 + t * 16);
      bw1c[t][0] = a1.x; bw1c[t][1] = a1.y; bw1c[t][2] = a1.z; bw1c[t][3] = a1.w;
      bw2c[t][0] = a2.x; bw2c[t][1] = a2.y; bw2c[t][2] = a2.z; bw2c[t][3] = a2.w;
    }
#pragma unroll
    for (int t = 0; t < 2; ++t)
      stpk4(XsL, wadrT[t], x[t][0], x[t][1], x[t][2], x[t][3]);
    __syncthreads();
    bf8 af[8];
#pragma unroll
    for (int ks = 0; ks < 8; ++ks)
      af[ks] = *(const bf8*)((const char*)XsL + radrT[ks]);
    f32x4 acc[2];
#pragma unroll
    for (int t = 0; t < 2; ++t) {
      f32x4 a0 = fzero, a1 = fzero;
#pragma unroll
      for (int ks = 0; ks < 8; ks += 2) {
        a0 = __builtin_amdgcn_mfma_f32_16x16x32_bf16(Wf1[t][ks], af[ks], a0, 0,
                                                     0, 0);
        a1 = __builtin_amdgcn_mfma_f32_16x16x32_bf16(Wf1[t][ks + 1],
                                                     af[ks + 1], a1, 0, 0, 0);
      }
      acc[t] = a0 + a1;
    }
#pragma unroll
    for (int t = 0; t < 2; ++t)
      stpk4(UL, wadrT[t], fast_tanh(acc[t][0] + bw1c[t][0]),
            fast_tanh(acc[t][1] + bw1c[t][1]),
            fast_tanh(acc[t][2] + bw1c[t][2]),
            fast_tanh(acc[t][3] + bw1c[t][3]));
    __syncthreads();
#pragma unroll
    for (int ks = 0; ks < 8; ++ks)
      af[ks] = *(const bf8*)((const char*)UL + radrT[ks]);
#pragma unroll
    for (int t = 0; t < 2; ++t) {
      f32x4 a0 = fzero, a1 = fzero;
#pragma unroll
      for (int ks = 0; ks < 8; ks += 2) {
        a0 = __builtin_amdgcn_mfma_f32_16x16x32_bf16(Wf2[t][ks], af[ks], a0, 0,
                                                     0, 0);
        a1 = __builtin_amdgcn_mfma_f32_16x16x32_bf16(Wf2[t][ks + 1],
                                                     af[ks + 1], a1, 0, 0, 0);
      }
      acc[t] = a0 + a1;
#pragma unroll
      for (int rg = 0; rg < 4; ++rg) v[t][rg] = acc[t][rg] + bw2c[t][rg];
    }
    float pn = 0.f, pm = 0.f;
#pragma unroll
    for (int t = 0; t < 2; ++t)
#pragma unroll
      for (int rg = 0; rg < 4; ++rg) {
        pn = fmaf(v[t][rg], v[t][rg], pn);
        pm = fmaf(nz[t][rg], nz[t][rg], pm);
      }
    pn += __shfl_xor(pn, 16);
    pn += __shfl_xor(pn, 32);
    pm += __shfl_xor(pm, 16);
    pm += __shfl_xor(pm, 32);
    if (q == 0) {
      atomicAdd(&gvv[0][l15][0], pn);
      atomicAdd(&gvv[0][l15][1], pm);
    }
    __syncthreads();
    const float wn = sqrtf(gvv[0][l15][0] + 1e-24f);
    const float sc =
        (wn < 1e-5f) ? 1e-4f / (sqrtf(gvv[0][l15][1] + 1e-24f) + 1e-12f) : 0.0f;
#pragma unroll
    for (int t = 0; t < 2; ++t)
#pragma unroll
      for (int rg = 0; rg < 4; ++rg) v[t][rg] = fmaf(sc, nz[t][rg], v[t][rg]);
    __syncthreads();
    if (tid < 16) *(float2*)gvv[0][tid] = make_float2(0.f, 0.f);
    __syncthreads();  // order zeroing before step0's early vv atomics
  }

  // ---- trace weight frags (Wf regs dead, reused by allocator) ----
  bf8 B1f[2][8], B2f[2][8];
#pragma unroll
  for (int t = 0; t < 2; ++t)
#pragma unroll
    for (int ks = 0; ks < 8; ++ks) {
      B1f[t][ks] =
          *(const bf8*)(WT + (size_t)(wrow + t * 16) * 256 + ks * 32 + q * 8);
      B2f[t][ks] =
          *(const bf8*)(Wp1s + (size_t)(wrow + t * 16) * 256 + ks * 32 + q * 8);
    }
  float ap[2][4], xacc[2][4], vacc[2][4];
#pragma unroll
  for (int t = 0; t < 2; ++t)
#pragma unroll
    for (int rg = 0; rg < 4; ++rg) ap[t][rg] = 0.0f;
  float md = 3.4e38f;
  const float cxv_t[4] = {0.0f, 0.5f * hs, 0.5f * hs, hs};
  const float cxa_t[4] = {0.0f, 0.0f, 0.25f * hs * hs, 0.5f * hs * hs};
  const float cva_t[4] = {0.0f, 0.5f * hs, 0.5f * hs, hs};

#pragma unroll 1
  for (int step = 0; step < 15; ++step) {
#pragma unroll
    for (int st = 0; st < 4; ++st) {
      const int p = st & 1;
      const float cxv = cxv_t[st], cxa = cxa_t[st], cva = cva_t[st];
      // A. stage position (packed b64); vv partial hoisted pre-barrier
      float vs[2][4], pv = 0.f;
#pragma unroll
      for (int t = 0; t < 2; ++t) {
        float sx[4];
#pragma unroll
        for (int rg = 0; rg < 4; ++rg) {
          vs[t][rg] = fmaf(cva, ap[t][rg], v[t][rg]);
          sx[rg] = x[t][rg] + cxv * v[t][rg] + cxa * ap[t][rg];
          pv = fmaf(vs[t][rg], vs[t][rg], pv);
        }
        stpk4(XsL, wadrT[t], sx[0], sx[1], sx[2], sx[3]);
      }
      pv += __shfl_xor(pv, 16);
      pv += __shfl_xor(pv, 32);
      if (q == 0) atomicAdd(&gvv[p][l15][1], pv);
      __syncthreads();  // B1
      // B. deferred closest-approach read (st0, step>0)
      if (st == 0 && step > 0) md = fminf(md, db[(step - 1) & 1][l15]);
      // mm1: H^T = Wp1^T * Xs^T
      bf8 af[8];
#pragma unroll
      for (int ks = 0; ks < 8; ++ks)
        af[ks] = *(const bf8*)((const char*)XsL + radrT[ks]);
      f32x4 acc[2];
#pragma unroll
      for (int t = 0; t < 2; ++t) {
        f32x4 a0 = fzero, a1 = fzero;
#pragma unroll
        for (int ks = 0; ks < 8; ks += 2) {
          a0 = __builtin_amdgcn_mfma_f32_16x16x32_bf16(B1f[t][ks], af[ks], a0,
                                                       0, 0, 0);
          a1 = __builtin_amdgcn_mfma_f32_16x16x32_bf16(B1f[t][ks + 1],
                                                       af[ks + 1], a1, 0, 0,
                                                       0);
        }
        acc[t] = a0 + a1;
        // U = sech^2 (wp2 absorbed into Wp1s) -> LDS (packed b64)
        stpk4(UL, wadrT[t], sech2(acc[t][0] + bp1c[t][0]),
              sech2(acc[t][1] + bp1c[t][1]), sech2(acc[t][2] + bp1c[t][2]),
              sech2(acc[t][3] + bp1c[t][3]));
      }
      if (tid < 16) *(float2*)gvv[p ^ 1][tid] = make_float2(0.f, 0.f);
      __syncthreads();  // B2
      // C. mm2: G^T = (wp2*Wp1) * U^T; deferred db zero (post-B2, race-free)
      if (st == 0 && step > 0 && tid < 16) db[(step - 1) & 1][tid] = 0.0f;
#pragma unroll
      for (int ks = 0; ks < 8; ++ks)
        af[ks] = *(const bf8*)((const char*)UL + radrT[ks]);
#pragma unroll
      for (int t = 0; t < 2; ++t) {
        f32x4 a0 = fzero, a1 = fzero;
#pragma unroll
        for (int ks = 0; ks < 8; ks += 2) {
          a0 = __builtin_amdgcn_mfma_f32_16x16x32_bf16(B2f[t][ks], af[ks], a0,
                                                       0, 0, 0);
          a1 = __builtin_amdgcn_mfma_f32_16x16x32_bf16(B2f[t][ks + 1],
                                                       af[ks + 1], a1, 0, 0,
                                                       0);
        }
        acc[t] = a0 + a1;
      }
      float pg = 0.f;
#pragma unroll
      for (int t = 0; t < 2; ++t)
#pragma unroll
        for (int rg = 0; rg < 4; ++rg) pg = fmaf(acc[t][rg], vs[t][rg], pg);
      pg += __shfl_xor(pg, 16);
      pg += __shfl_xor(pg, 32);
      if (q == 0) atomicAdd(&gvv[p][l15][0], pg);
      __syncthreads();  // B3
      // D. broadcast read (b64) + accel + RK4 accumulation
      const float2 r2 = *(const float2*)gvv[p][l15];
      const float gv = r2.x, vv = r2.y;
#pragma unroll
      for (int t = 0; t < 2; ++t)
#pragma unroll
        for (int rg = 0; rg < 4; ++rg) {
          const float a = -gv * vs[t][rg] + 0.5f * vv * acc[t][rg];
          ap[t][rg] = a;
          if (st == 0) {
            xacc[t][rg] = a;
            vacc[t][rg] = a;
          } else if (st < 3) {
            xacc[t][rg] += a;
            vacc[t][rg] += 2.0f * a;
          } else {
            vacc[t][rg] += a;
          }
        }
      // E. st3: step update + distance partials (read deferred past next B1)
      if (st == 3) {
        const int sp = step & 1;
        float pd = 0.f;
#pragma unroll
        for (int t = 0; t < 2; ++t)
#pragma unroll
          for (int rg = 0; rg < 4; ++rg) {
            const float xn =
                x[t][rg] + hs * v[t][rg] + (hs * hs / 6.0f) * xacc[t][rg];
            const float vn = v[t][rg] + (hs / 6.0f) * vacc[t][rg];
            x[t][rg] = xn;
            v[t][rg] = vn;
            const float dd = xn - ze[t][rg];
            pd = fmaf(dd, dd, pd);
          }
        pd += __shfl_xor(pd, 16);
        pd += __shfl_xor(pd, 32);
        if (q == 0) atomicAdd(&db[sp][l15], pd);
      }
    }
  }
  __syncthreads();  // final step's distance atomics
  md = fminf(md, db[14 & 1][l15]);
  if (w == 0) {
    const float s = red16(md);  // sum rows 0..15 within 16-lane group
    if (tid == 0) atomicAdd(out, s * (1.0f / 4096.0f));
  }
}

}  // namespace

extern "C" void kernel_launch(void* const* d_in, const int* in_sizes, int n_in,
                              void* d_out, int out_size, void* d_ws,
                              size_t ws_size, hipStream_t stream) {
  (void)in_sizes; (void)n_in; (void)out_size; (void)ws_size;
  const float* x_start = (const float*)d_in[0];
  const float* x_end = (const float*)d_in[1];
  const float* noise = (const float*)d_in[2];
  const float* W1 = (const float*)d_in[3];
  const float* b1 = (const float*)d_in[4];
  const float* W2 = (const float*)d_in[5];
  const float* b2 = (const float*)d_in[6];
  const float* Ww1 = (const float*)d_in[7];
  const float* bw1 = (const float*)d_in[8];
  const float* Ww2 = (const float*)d_in[9];
  const float* bw2 = (const float*)d_in[10];
  const float* Wp1 = (const float*)d_in[11];
  const float* bp1 = (const float*)d_in[12];
  const float* wp2 = (const float*)d_in[13];
  float* out = (float*)d_out;

  // workspace layout (~61 MB)
  float* Xf = (float*)d_ws;                        // z_s  4096*256 f32
  float* ZEf = Xf + (size_t)4096 * 256;            // z_e
  short* XSb = (short*)(ZEf + (size_t)4096 * 256); // x bf16 8192*2048
  short* H1b = XSb + (size_t)8192 * 2048;          // enc hidden bf16 8192*1024
  short* W1T = H1b + (size_t)8192 * 1024;          // 1024*2048
  short* W2T = W1T + (size_t)1024 * 2048;          // 256*1024
  short* Ww1T = W2T + (size_t)256 * 1024;
  short* Ww2T = Ww1T + 65536;
  short* WpT = Ww2T + 65536;                       // Wp1^T
  short* Wp1s = WpT + 65536;                       // wp2-scaled Wp1 row-major

  const dim3 blk(256);

  prep_all<<<4608, blk, 0, stream>>>(x_start, x_end, W1, W2, Ww1, Ww2, Wp1,
                                     wp2, XSb, W1T, W2T, Ww1T, Ww2T, WpT,
                                     Wp1s, out);
  gemm128_tanh<<<dim3(8, 64), blk, 0, stream>>>(XSb, W1T, b1, H1b, 8192, 1024,
                                                2048);
  gemm64_enc2<<<dim3(4, 128), blk, 0, stream>>>(H1b, W2T, b2, Xf, ZEf, 8192,
                                                256, 1024);
  trace_fused<<<256, dim3(512), 0, stream>>>(Xf, ZEf, noise, WpT, Wp1s, Ww1T,
                                             Ww2T, bw1, bw2, bp1, out);
}

// Round 5
// 314.375 us; speedup vs baseline: 1.0387x; 1.0181x over previous
//
// Round 9 (2nd resubmit — R3/R4 benches failed on GPU acquisition, no data):
// swizzle mask fix. R8's smask=((l15&7)<<2)^(l15&3) dropped l15_2
// from the bank group -> 2-way b128-read / 4-way b64-write phase conflicts
// (14M SQ_LDS_BANK_CONFLICT, ~2x LDS serialization). smask=l15&7 makes
// slot%8 bijective in l15 low3 within every 8-lane read phase (reads
// conflict-free); writes go 4-way->2-way (2-way is structural floor).
// Only the mask expression changed vs R8.

#include <hip/hip_runtime.h>
#include <math.h>

typedef short bf8 __attribute__((ext_vector_type(8)));   // 8 bf16 = 4 VGPR
typedef short s4v __attribute__((ext_vector_type(4)));   // 4 bf16 = 8 B
typedef float f32x4 __attribute__((ext_vector_type(4))); // MFMA acc

namespace {

constexpr float H_STEP = 1.0f / 15.0f;

__device__ inline short f2bf(float f) {  // RNE f32 -> bf16
  unsigned u = __float_as_uint(f);
  u += 0x7fffu + ((u >> 16) & 1u);
  return (short)(u >> 16);
}

__device__ inline float fast_tanh(float x) {
  const float ax = fabsf(x);
  const float e = __expf(-2.0f * ax);
  const float t = (1.0f - e) * __builtin_amdgcn_rcpf(1.0f + e);
  return copysignf(t, x);
}

// 1 - tanh(x)^2 = 4 e / (1+e)^2, e = exp(-2|x|)
__device__ inline float sech2(float x) {
  const float e = __expf(-2.0f * fabsf(x));
  const float r = __builtin_amdgcn_rcpf(1.0f + e);
  return 4.0f * e * r * r;
}

// sum over each 16-lane group via DPP row_ror 1/2/4/8 (final output reduce)
template <int CTRL>
__device__ inline float dppadd(float v) {
  return v + __int_as_float(__builtin_amdgcn_update_dpp(
                 0, __float_as_int(v), CTRL, 0xF, 0xF, true));
}
__device__ inline float red16(float v) {
  v = dppadd<0x121>(v);
  v = dppadd<0x122>(v);
  v = dppadd<0x124>(v);
  v = dppadd<0x128>(v);
  return v;
}

// async global->LDS, 16B per lane. LDS dest = wave-uniform base + lane*16.
__device__ inline void async16(const void* g, void* l) {
  __builtin_amdgcn_global_load_lds((__attribute__((address_space(1))) void*)g,
                                   (__attribute__((address_space(3))) void*)l,
                                   16, 0, 0);
}

// pack 4 f32 -> 4 bf16, single ds_write_b64 at byte offset
__device__ inline void stpk4(short* base, int byteoff, float a, float b,
                             float c, float d) {
  s4v s;
  s[0] = f2bf(a);
  s[1] = f2bf(b);
  s[2] = f2bf(c);
  s[3] = f2bf(d);
  *(s4v*)((char*)base + byteoff) = s;
}

// ---------------- one-shot prep: inputs + all weight converts ----------------
// blocks [0,2048): x_start/x_end -> XSb [8192][2048] bf16 (grid-stride x8)
// [2048,4096): W1^T  [4096,4352): W2^T  [4352,4416): Ww1^T
// [4416,4480): Ww2^T [4480,4544): Wp1^T [4544,4608): wp2-scaled Wp1 copy
__global__ __launch_bounds__(256) void prep_all(
    const float* __restrict__ xs, const float* __restrict__ xe,
    const float* __restrict__ W1, const float* __restrict__ W2,
    const float* __restrict__ Ww1, const float* __restrict__ Ww2,
    const float* __restrict__ Wp1, const float* __restrict__ wp2,
    short* __restrict__ XSb, short* __restrict__ W1T, short* __restrict__ W2T,
    short* __restrict__ Ww1T, short* __restrict__ Ww2T,
    short* __restrict__ WpT, short* __restrict__ Wp1s,
    float* __restrict__ outz) {
  __shared__ float tile[32][33];
  const int id = blockIdx.x;
  if (id < 2048) {
    if (id == 0 && threadIdx.x == 0) *outz = 0.0f;  // folded memset
    const long n = (long)8192 * 2048, half = n >> 1;
    long i = ((long)id * 256 + threadIdx.x) * 4;
    const long stride = (long)2048 * 1024;
    for (; i < n; i += stride) {
      const float* s = (i < half) ? (xs + i) : (xe + (i - half));
      const float4 f = *(const float4*)s;
      ushort4 o;
      o.x = (unsigned short)f2bf(f.x);
      o.y = (unsigned short)f2bf(f.y);
      o.z = (unsigned short)f2bf(f.z);
      o.w = (unsigned short)f2bf(f.w);
      *(ushort4*)(XSb + i) = o;
    }
    return;
  }
  const int tr = threadIdx.x >> 5, tc = threadIdx.x & 31;
  const float* src;
  short* dst;
  int K, N, kt, nt;
  if (id < 4096) {
    src = W1; dst = W1T; K = 2048; N = 1024; kt = (id - 2048) >> 5; nt = (id - 2048) & 31;
  } else if (id < 4352) {
    src = W2; dst = W2T; K = 1024; N = 256; kt = (id - 4096) >> 3; nt = (id - 4096) & 7;
  } else if (id < 4416) {
    src = Ww1; dst = Ww1T; K = 256; N = 256; kt = (id - 4352) >> 3; nt = (id - 4352) & 7;
  } else if (id < 4480) {
    src = Ww2; dst = Ww2T; K = 256; N = 256; kt = (id - 4416) >> 3; nt = (id - 4416) & 7;
  } else if (id < 4544) {
    src = Wp1; dst = WpT; K = 256; N = 256; kt = (id - 4480) >> 3; nt = (id - 4480) & 7;
  } else {  // wp2-scaled row-major copy
    const int lid = id - 4544;
    const int k0 = (lid >> 3) * 32, n0 = (lid & 7) * 32;
#pragma unroll
    for (int i = 0; i < 32; i += 8) {
      const size_t o = (size_t)(k0 + tr + i) * 256 + n0 + tc;
      Wp1s[o] = f2bf(Wp1[o] * wp2[n0 + tc]);
    }
    return;
  }
  const int k0 = kt * 32, n0 = nt * 32;
#pragma unroll
  for (int i = 0; i < 32; i += 8)
    tile[tr + i][tc] = src[(size_t)(k0 + tr + i) * N + n0 + tc];
  __syncthreads();
#pragma unroll
  for (int i = 0; i < 32; i += 8)
    dst[(size_t)(n0 + tr + i) * K + k0 + tc] = f2bf(tile[tc][tr + i]);
}

// ---------------- bf16 TN GEMMs, global_load_lds staging ----------------

// 128x128 tile, BK=64, tanh->bf16 epilogue (encoder L1)
__global__ __launch_bounds__(256) void gemm128_tanh(
    const short* __restrict__ A, const short* __restrict__ Bt,
    const float* __restrict__ bias, short* __restrict__ Cb, int M, int N,
    int K) {
  __shared__ __align__(16) short As[2 * 128 * 32];
  __shared__ __align__(16) short Bs[2 * 128 * 32];
  const int tid = threadIdx.x;
  const int w = tid >> 6, lane = tid & 63, q = lane >> 4, l15 = lane & 15;
  const int wm = (w >> 1) * 64, wn = (w & 1) * 64;
  const int m0 = blockIdx.y * 128, n0 = blockIdx.x * 128;
  const f32x4 fzero = {0.0f, 0.0f, 0.0f, 0.0f};
  f32x4 acc[4][4];
#pragma unroll
  for (int mt = 0; mt < 4; ++mt)
#pragma unroll
    for (int nt = 0; nt < 4; ++nt) acc[mt][nt] = fzero;

  for (int k0 = 0; k0 < K; k0 += 64) {
#pragma unroll
    for (int kcb = 0; kcb < 2; ++kcb)
#pragma unroll
      for (int j = 0; j < 2; ++j) {
        const int c = w * 128 + j * 64 + lane;
        async16(A + (size_t)(m0 + (c >> 2)) * K + k0 + kcb * 32 + (c & 3) * 8,
                &As[kcb * 4096 + (w * 128 + j * 64) * 8]);
        async16(Bt + (size_t)(n0 + (c >> 2)) * K + k0 + kcb * 32 + (c & 3) * 8,
                &Bs[kcb * 4096 + (w * 128 + j * 64) * 8]);
      }
    __syncthreads();
#pragma unroll
    for (int kcb = 0; kcb < 2; ++kcb) {
      bf8 af[4], bfr[4];
#pragma unroll
      for (int mt = 0; mt < 4; ++mt)
        af[mt] =
            *(const bf8*)&As[kcb * 4096 + (wm + mt * 16 + l15) * 32 + q * 8];
#pragma unroll
      for (int nt = 0; nt < 4; ++nt)
        bfr[nt] =
            *(const bf8*)&Bs[kcb * 4096 + (wn + nt * 16 + l15) * 32 + q * 8];
#pragma unroll
      for (int mt = 0; mt < 4; ++mt)
#pragma unroll
        for (int nt = 0; nt < 4; ++nt)
          acc[mt][nt] = __builtin_amdgcn_mfma_f32_16x16x32_bf16(
              af[mt], bfr[nt], acc[mt][nt], 0, 0, 0);
    }
    __syncthreads();
  }
#pragma unroll
  for (int mt = 0; mt < 4; ++mt)
#pragma unroll
    for (int nt = 0; nt < 4; ++nt) {
      const int col = n0 + wn + nt * 16 + l15;
      const float bcol = bias[col];
#pragma unroll
      for (int rg = 0; rg < 4; ++rg) {
        const int row = m0 + wm + mt * 16 + q * 4 + rg;
        Cb[(size_t)row * N + col] = f2bf(fast_tanh(acc[mt][nt][rg] + bcol));
      }
    }
}

// 64x64 tile, BK=64; rows<4096 -> z_s, rows>=4096 -> z_e (both f32)
__global__ __launch_bounds__(256) void gemm64_enc2(
    const short* __restrict__ A, const short* __restrict__ Bt,
    const float* __restrict__ bias, float* __restrict__ Zs,
    float* __restrict__ Ze, int M, int N, int K) {
  __shared__ __align__(16) short As[2 * 64 * 32];
  __shared__ __align__(16) short Bs[2 * 64 * 32];
  const int tid = threadIdx.x;
  const int w = tid >> 6, lane = tid & 63, q = lane >> 4, l15 = lane & 15;
  const int wm = (w >> 1) * 32, wn = (w & 1) * 32;
  const int m0 = blockIdx.y * 64, n0 = blockIdx.x * 64;
  const f32x4 fzero = {0.0f, 0.0f, 0.0f, 0.0f};
  f32x4 acc[2][2];
#pragma unroll
  for (int mt = 0; mt < 2; ++mt)
#pragma unroll
    for (int nt = 0; nt < 2; ++nt) acc[mt][nt] = fzero;

  for (int k0 = 0; k0 < K; k0 += 64) {
    const int c = w * 64 + lane;
#pragma unroll
    for (int kcb = 0; kcb < 2; ++kcb) {
      async16(A + (size_t)(m0 + (c >> 2)) * K + k0 + kcb * 32 + (c & 3) * 8,
              &As[kcb * 2048 + (w * 64) * 8]);
      async16(Bt + (size_t)(n0 + (c >> 2)) * K + k0 + kcb * 32 + (c & 3) * 8,
              &Bs[kcb * 2048 + (w * 64) * 8]);
    }
    __syncthreads();
#pragma unroll
    for (int kcb = 0; kcb < 2; ++kcb) {
      bf8 af[2], bfr[2];
#pragma unroll
      for (int mt = 0; mt < 2; ++mt)
        af[mt] =
            *(const bf8*)&As[kcb * 2048 + (wm + mt * 16 + l15) * 32 + q * 8];
#pragma unroll
      for (int nt = 0; nt < 2; ++nt)
        bfr[nt] =
            *(const bf8*)&Bs[kcb * 2048 + (wn + nt * 16 + l15) * 32 + q * 8];
#pragma unroll
      for (int mt = 0; mt < 2; ++mt)
#pragma unroll
        for (int nt = 0; nt < 2; ++nt)
          acc[mt][nt] = __builtin_amdgcn_mfma_f32_16x16x32_bf16(
              af[mt], bfr[nt], acc[mt][nt], 0, 0, 0);
    }
    __syncthreads();
  }
#pragma unroll
  for (int mt = 0; mt < 2; ++mt)
#pragma unroll
    for (int nt = 0; nt < 2; ++nt) {
      const int col = n0 + wn + nt * 16 + l15;
      const float bcol = bias[col];
#pragma unroll
      for (int rg = 0; rg < 4; ++rg) {
        const int row = m0 + wm + mt * 16 + q * 4 + rg;
        const float val = acc[mt][nt][rg] + bcol;
        if (row < 4096)
          Zs[(size_t)row * N + col] = val;
        else
          Ze[(size_t)(row - 4096) * N + col] = val;
      }
    }
}

// ---------------- fused wind + fallback + trace (transposed layout) ----------
// 256 blocks x 512 threads. MFMA operands swapped: D = W_frag * X_frag, so
// C-layout gives row r = l15, cols c = w*32 + t*16 + q*4 + rg. Per-row
// reductions: in-thread 8-term sum + shfl_xor(16,32) + 1 LDS atomic (q==0).
// LDS tiles [16 rows][32 slots of 16B], slot swizzle slot^(l15&7):
// b128 reads conflict-free per 8-lane phase; b64 writes 2-way (floor).

__global__ __launch_bounds__(512, 2) void trace_fused(
    const float* __restrict__ Xg, const float* __restrict__ ZEg,
    const float* __restrict__ NZg, const short* __restrict__ WT,
    const short* __restrict__ Wp1s, const short* __restrict__ Ww1T,
    const short* __restrict__ Ww2T, const float* __restrict__ bw1,
    const float* __restrict__ bw2, const float* __restrict__ bp1,
    float* __restrict__ out) {
  constexpr float hs = H_STEP;
  __shared__ __align__(16) short XsL[4096];
  __shared__ __align__(16) short UL[4096];
  __shared__ __align__(16) float gvv[2][16][2];  // [parity][row][gv, vv]
  __shared__ __align__(16) float db[2][16];
  const int tid = threadIdx.x;
  const int w = tid >> 6, lane = tid & 63, q = lane >> 4, l15 = lane & 15;
  const int r0 = blockIdx.x * 16;
  const int col0 = w * 32 + q * 4;   // feature-col base (t adds 16, rg adds)
  const int wrow = w * 32 + l15;     // weight-frag row base (t adds 16)

  if (tid < 16) {
    *(float2*)gvv[0][tid] = make_float2(0.f, 0.f);
    *(float2*)gvv[1][tid] = make_float2(0.f, 0.f);
    db[0][tid] = 0.f;
    db[1][tid] = 0.f;
  }

  // LDS addresses (bytes). Shared by XsL and UL (same geometry).
  // smask = l15&7: slot%8 bijective in l15 low3 within each 8-lane phase.
  const int smask = l15 & 7;
  int wadrT[2], radrT[8];
#pragma unroll
  for (int t = 0; t < 2; ++t) {
    const int slot = w * 4 + t * 2 + (q >> 1);
    wadrT[t] = (l15 * 32 + (slot ^ smask)) * 16 + (q & 1) * 8;
  }
#pragma unroll
  for (int ks = 0; ks < 8; ++ks)
    radrT[ks] = (l15 * 32 + ((ks * 4 + q) ^ smask)) * 16;

  float x[2][4], ze[2][4], nz[2][4];
#pragma unroll
  for (int t = 0; t < 2; ++t) {
    const size_t off = (size_t)(r0 + l15) * 256 + col0 + t * 16;
    const float4 xa = *(const float4*)(Xg + off);
    const float4 za = *(const float4*)(ZEg + off);
    const float4 na = *(const float4*)(NZg + off);
    x[t][0] = xa.x; x[t][1] = xa.y; x[t][2] = xa.z; x[t][3] = xa.w;
    ze[t][0] = za.x; ze[t][1] = za.y; ze[t][2] = za.z; ze[t][3] = za.w;
    nz[t][0] = na.x; nz[t][1] = na.y; nz[t][2] = na.z; nz[t][3] = na.w;
  }
  float bp1c[2][4];
#pragma unroll
  for (int t = 0; t < 2; ++t) {
    const float4 pa = *(const float4*)(bp1 + col0 + t * 16);
    bp1c[t][0] = pa.x; bp1c[t][1] = pa.y; bp1c[t][2] = pa.z; bp1c[t][3] = pa.w;
  }
  const f32x4 fzero = {0.0f, 0.0f, 0.0f, 0.0f};

  // ---- wind MLP + degenerate-wind fallback ----
  float v[2][4];
  {
    bf8 Wf1[2][8], Wf2[2][8];
#pragma unroll
    for (int t = 0; t < 2; ++t)
#pragma unroll
      for (int ks = 0; ks < 8; ++ks) {
        Wf1[t][ks] =
            *(const bf8*)(Ww1T + (size_t)(wrow + t * 16) * 256 + ks * 32 + q * 8);
        Wf2[t][ks] =
            *(const bf8*)(Ww2T + (size_t)(wrow + t * 16) * 256 + ks * 32 + q * 8);
      }
    float bw1c[2][4], bw2c[2][4];
#pragma unroll
    for (int t = 0; t < 2; ++t) {
      const float4 a1 = *(const float4*)(bw1 + col0 + t * 16);
      const float4 a2 = *(const float4*)(bw2 + col0 + t * 16);
      bw1c[t][0] = a1.x; bw1c[t][1] = a1.y; bw1c[t][2] = a1.z; bw1c[t][3] = a1.w;
      bw2c[t][0] = a2.x; bw2c[t][1] = a2.y; bw2c[t][2] = a2.z; bw2c[t][3] = a2.w;
    }
#pragma unroll
    for (int t = 0; t < 2; ++t)
      stpk4(XsL, wadrT[t], x[t][0], x[t][1], x[t][2], x[t][3]);
    __syncthreads();
    bf8 af[8];
#pragma unroll
    for (int ks = 0; ks < 8; ++ks)
      af[ks] = *(const bf8*)((const char*)XsL + radrT[ks]);
    f32x4 acc[2];
#pragma unroll
    for (int t = 0; t < 2; ++t) {
      f32x4 a0 = fzero, a1 = fzero;
#pragma unroll
      for (int ks = 0; ks < 8; ks += 2) {
        a0 = __builtin_amdgcn_mfma_f32_16x16x32_bf16(Wf1[t][ks], af[ks], a0, 0,
                                                     0, 0);
        a1 = __builtin_amdgcn_mfma_f32_16x16x32_bf16(Wf1[t][ks + 1],
                                                     af[ks + 1], a1, 0, 0, 0);
      }
      acc[t] = a0 + a1;
    }
#pragma unroll
    for (int t = 0; t < 2; ++t)
      stpk4(UL, wadrT[t], fast_tanh(acc[t][0] + bw1c[t][0]),
            fast_tanh(acc[t][1] + bw1c[t][1]),
            fast_tanh(acc[t][2] + bw1c[t][2]),
            fast_tanh(acc[t][3] + bw1c[t][3]));
    __syncthreads();
#pragma unroll
    for (int ks = 0; ks < 8; ++ks)
      af[ks] = *(const bf8*)((const char*)UL + radrT[ks]);
#pragma unroll
    for (int t = 0; t < 2; ++t) {
      f32x4 a0 = fzero, a1 = fzero;
#pragma unroll
      for (int ks = 0; ks < 8; ks += 2) {
        a0 = __builtin_amdgcn_mfma_f32_16x16x32_bf16(Wf2[t][ks], af[ks], a0, 0,
                                                     0, 0);
        a1 = __builtin_amdgcn_mfma_f32_16x16x32_bf16(Wf2[t][ks + 1],
                                                     af[ks + 1], a1, 0, 0, 0);
      }
      acc[t] = a0 + a1;
#pragma unroll
      for (int rg = 0; rg < 4; ++rg) v[t][rg] = acc[t][rg] + bw2c[t][rg];
    }
    float pn = 0.f, pm = 0.f;
#pragma unroll
    for (int t = 0; t < 2; ++t)
#pragma unroll
      for (int rg = 0; rg < 4; ++rg) {
        pn = fmaf(v[t][rg], v[t][rg], pn);
        pm = fmaf(nz[t][rg], nz[t][rg], pm);
      }
    pn += __shfl_xor(pn, 16);
    pn += __shfl_xor(pn, 32);
    pm += __shfl_xor(pm, 16);
    pm += __shfl_xor(pm, 32);
    if (q == 0) {
      atomicAdd(&gvv[0][l15][0], pn);
      atomicAdd(&gvv[0][l15][1], pm);
    }
    __syncthreads();
    const float wn = sqrtf(gvv[0][l15][0] + 1e-24f);
    const float sc =
        (wn < 1e-5f) ? 1e-4f / (sqrtf(gvv[0][l15][1] + 1e-24f) + 1e-12f) : 0.0f;
#pragma unroll
    for (int t = 0; t < 2; ++t)
#pragma unroll
      for (int rg = 0; rg < 4; ++rg) v[t][rg] = fmaf(sc, nz[t][rg], v[t][rg]);
    __syncthreads();
    if (tid < 16) *(float2*)gvv[0][tid] = make_float2(0.f, 0.f);
    __syncthreads();  // order zeroing before step0's early vv atomics
  }

  // ---- trace weight frags (Wf regs dead, reused by allocator) ----
  bf8 B1f[2][8], B2f[2][8];
#pragma unroll
  for (int t = 0; t < 2; ++t)
#pragma unroll
    for (int ks = 0; ks < 8; ++ks) {
      B1f[t][ks] =
          *(const bf8*)(WT + (size_t)(wrow + t * 16) * 256 + ks * 32 + q * 8);
      B2f[t][ks] =
          *(const bf8*)(Wp1s + (size_t)(wrow + t * 16) * 256 + ks * 32 + q * 8);
    }
  float ap[2][4], xacc[2][4], vacc[2][4];
#pragma unroll
  for (int t = 0; t < 2; ++t)
#pragma unroll
    for (int rg = 0; rg < 4; ++rg) ap[t][rg] = 0.0f;
  float md = 3.4e38f;
  const float cxv_t[4] = {0.0f, 0.5f * hs, 0.5f * hs, hs};
  const float cxa_t[4] = {0.0f, 0.0f, 0.25f * hs * hs, 0.5f * hs * hs};
  const float cva_t[4] = {0.0f, 0.5f * hs, 0.5f * hs, hs};

#pragma unroll 1
  for (int step = 0; step < 15; ++step) {
#pragma unroll
    for (int st = 0; st < 4; ++st) {
      const int p = st & 1;
      const float cxv = cxv_t[st], cxa = cxa_t[st], cva = cva_t[st];
      // A. stage position (packed b64); vv partial hoisted pre-barrier
      float vs[2][4], pv = 0.f;
#pragma unroll
      for (int t = 0; t < 2; ++t) {
        float sx[4];
#pragma unroll
        for (int rg = 0; rg < 4; ++rg) {
          vs[t][rg] = fmaf(cva, ap[t][rg], v[t][rg]);
          sx[rg] = x[t][rg] + cxv * v[t][rg] + cxa * ap[t][rg];
          pv = fmaf(vs[t][rg], vs[t][rg], pv);
        }
        stpk4(XsL, wadrT[t], sx[0], sx[1], sx[2], sx[3]);
      }
      pv += __shfl_xor(pv, 16);
      pv += __shfl_xor(pv, 32);
      if (q == 0) atomicAdd(&gvv[p][l15][1], pv);
      __syncthreads();  // B1
      // B. deferred closest-approach read (st0, step>0)
      if (st == 0 && step > 0) md = fminf(md, db[(step - 1) & 1][l15]);
      // mm1: H^T = Wp1^T * Xs^T
      bf8 af[8];
#pragma unroll
      for (int ks = 0; ks < 8; ++ks)
        af[ks] = *(const bf8*)((const char*)XsL + radrT[ks]);
      f32x4 acc[2];
#pragma unroll
      for (int t = 0; t < 2; ++t) {
        f32x4 a0 = fzero, a1 = fzero;
#pragma unroll
        for (int ks = 0; ks < 8; ks += 2) {
          a0 = __builtin_amdgcn_mfma_f32_16x16x32_bf16(B1f[t][ks], af[ks], a0,
                                                       0, 0, 0);
          a1 = __builtin_amdgcn_mfma_f32_16x16x32_bf16(B1f[t][ks + 1],
                                                       af[ks + 1], a1, 0, 0,
                                                       0);
        }
        acc[t] = a0 + a1;
        // U = sech^2 (wp2 absorbed into Wp1s) -> LDS (packed b64)
        stpk4(UL, wadrT[t], sech2(acc[t][0] + bp1c[t][0]),
              sech2(acc[t][1] + bp1c[t][1]), sech2(acc[t][2] + bp1c[t][2]),
              sech2(acc[t][3] + bp1c[t][3]));
      }
      if (tid < 16) *(float2*)gvv[p ^ 1][tid] = make_float2(0.f, 0.f);
      __syncthreads();  // B2
      // C. mm2: G^T = (wp2*Wp1) * U^T; deferred db zero (post-B2, race-free)
      if (st == 0 && step > 0 && tid < 16) db[(step - 1) & 1][tid] = 0.0f;
#pragma unroll
      for (int ks = 0; ks < 8; ++ks)
        af[ks] = *(const bf8*)((const char*)UL + radrT[ks]);
#pragma unroll
      for (int t = 0; t < 2; ++t) {
        f32x4 a0 = fzero, a1 = fzero;
#pragma unroll
        for (int ks = 0; ks < 8; ks += 2) {
          a0 = __builtin_amdgcn_mfma_f32_16x16x32_bf16(B2f[t][ks], af[ks], a0,
                                                       0, 0, 0);
          a1 = __builtin_amdgcn_mfma_f32_16x16x32_bf16(B2f[t][ks + 1],
                                                       af[ks + 1], a1, 0, 0,
                                                       0);
        }
        acc[t] = a0 + a1;
      }
      float pg = 0.f;
#pragma unroll
      for (int t = 0; t < 2; ++t)
#pragma unroll
        for (int rg = 0; rg < 4; ++rg) pg = fmaf(acc[t][rg], vs[t][rg], pg);
      pg += __shfl_xor(pg, 16);
      pg += __shfl_xor(pg, 32);
      if (q == 0) atomicAdd(&gvv[p][l15][0], pg);
      __syncthreads();  // B3
      // D. broadcast read (b64) + accel + RK4 accumulation
      const float2 r2 = *(const float2*)gvv[p][l15];
      const float gv = r2.x, vv = r2.y;
#pragma unroll
      for (int t = 0; t < 2; ++t)
#pragma unroll
        for (int rg = 0; rg < 4; ++rg) {
          const float a = -gv * vs[t][rg] + 0.5f * vv * acc[t][rg];
          ap[t][rg] = a;
          if (st == 0) {
            xacc[t][rg] = a;
            vacc[t][rg] = a;
          } else if (st < 3) {
            xacc[t][rg] += a;
            vacc[t][rg] += 2.0f * a;
          } else {
            vacc[t][rg] += a;
          }
        }
      // E. st3: step update + distance partials (read deferred past next B1)
      if (st == 3) {
        const int sp = step & 1;
        float pd = 0.f;
#pragma unroll
        for (int t = 0; t < 2; ++t)
#pragma unroll
          for (int rg = 0; rg < 4; ++rg) {
            const float xn =
                x[t][rg] + hs * v[t][rg] + (hs * hs / 6.0f) * xacc[t][rg];
            const float vn = v[t][rg] + (hs / 6.0f) * vacc[t][rg];
            x[t][rg] = xn;
            v[t][rg] = vn;
            const float dd = xn - ze[t][rg];
            pd = fmaf(dd, dd, pd);
          }
        pd += __shfl_xor(pd, 16);
        pd += __shfl_xor(pd, 32);
        if (q == 0) atomicAdd(&db[sp][l15], pd);
      }
    }
  }
  __syncthreads();  // final step's distance atomics
  md = fminf(md, db[14 & 1][l15]);
  if (w == 0) {
    const float s = red16(md);  // sum rows 0..15 within 16-lane group
    if (tid == 0) atomicAdd(out, s * (1.0f / 4096.0f));
  }
}

}  // namespace

extern "C" void kernel_launch(void* const* d_in, const int* in_sizes, int n_in,
                              void* d_out, int out_size, void* d_ws,
                              size_t ws_size, hipStream_t stream) {
  (void)in_sizes; (void)n_in; (void)out_size; (void)ws_size;
  const float* x_start = (const float*)d_in[0];
  const float* x_end = (const float*)d_in[1];
  const float* noise = (const float*)d_in[2];
  const float* W1 = (const float*)d_in[3];
  const float* b1 = (const float*)d_in[4];
  const float* W2 = (const float*)d_in[5];
  const float* b2 = (const float*)d_in[6];
  const float* Ww1 = (const float*)d_in[7];
  const float* bw1 = (const float*)d_in[8];
  const float* Ww2 = (const float*)d_in[9];
  const float* bw2 = (const float*)d_in[10];
  const float* Wp1 = (const float*)d_in[11];
  const float* bp1 = (const float*)d_in[12];
  const float* wp2 = (const float*)d_in[13];
  float* out = (float*)d_out;

  // workspace layout (~61 MB)
  float* Xf = (float*)d_ws;                        // z_s  4096*256 f32
  float* ZEf = Xf + (size_t)4096 * 256;            // z_e
  short* XSb = (short*)(ZEf + (size_t)4096 * 256); // x bf16 8192*2048
  short* H1b = XSb + (size_t)8192 * 2048;          // enc hidden bf16 8192*1024
  short* W1T = H1b + (size_t)8192 * 1024;          // 1024*2048
  short* W2T = W1T + (size_t)1024 * 2048;          // 256*1024
  short* Ww1T = W2T + (size_t)256 * 1024;
  short* Ww2T = Ww1T + 65536;
  short* WpT = Ww2T + 65536;                       // Wp1^T
  short* Wp1s = WpT + 65536;                       // wp2-scaled Wp1 row-major

  const dim3 blk(256);

  prep_all<<<4608, blk, 0, stream>>>(x_start, x_end, W1, W2, Ww1, Ww2, Wp1,
                                     wp2, XSb, W1T, W2T, Ww1T, Ww2T, WpT,
                                     Wp1s, out);
  gemm128_tanh<<<dim3(8, 64), blk, 0, stream>>>(XSb, W1T, b1, H1b, 8192, 1024,
                                                2048);
  gemm64_enc2<<<dim3(4, 128), blk, 0, stream>>>(H1b, W2T, b2, Xf, ZEf, 8192,
                                                256, 1024);
  trace_fused<<<256, dim3(512), 0, stream>>>(Xf, ZEf, noise, WpT, Wp1s, Ww1T,
                                             Ww2T, bw1, bw2, bp1, out);
}